// Round 5
// baseline (546.126 us; speedup 1.0000x reference)
//
#include <hip/hip_runtime.h>

#define NPATH  2048
#define DIM    64
#define NSTEPS 500

// FOUR waves per path (one block = one path). Wave w holds a 32-column
// half-row of A (w=0,1) or C (w=2,3): 32 matrix floats/lane => ~60 VGPR,
// fits the allocator's 8-waves/EU budget => truly register-resident AND
// 8 waves/SIMD occupancy. Per step: 8 broadcast ds_read_b128 + 32 FMAs per
// wave; waves 1-3 publish partials (stride-1 LDS); wave 0 combines, applies
// dt/noise, NT-stores ys, republishes x. dW prefetch ring on wave 0.
__global__ __launch_bounds__(256) void sde_euler_kernel(
    const float* __restrict__ x0,
    const float* __restrict__ dW,
    const float* __restrict__ drift,
    const float* __restrict__ drift_bias,
    const float* __restrict__ diffusion,
    const float* __restrict__ diffusion_bias,
    const float* __restrict__ ts,
    float* __restrict__ out)
{
    __shared__ __align__(16) float xs[DIM];      // broadcast state row
    __shared__ float ps[3][DIM];                 // partials from waves 1..3
    __shared__ float2 dtp[NSTEPS + 1];           // {dt, sqrt(dt)} per step

    const int lane = threadIdx.x & 63;
    const int wave = threadIdx.x >> 6;
    const int half = wave & 1;                   // k-half this wave covers
    const int path = blockIdx.x;

    // (dt, sqrt(dt)) table — dt = ts[i+1]-ts[i] in f32, matching reference
    for (int i = threadIdx.x; i < NSTEPS; i += 256) {
        const float d = ts[i + 1] - ts[i];
        dtp[i] = make_float2(d, sqrtf(d));
    }
    if (threadIdx.x == 0) dtp[NSTEPS] = make_float2(0.f, 0.f);

    // This wave's half-row: A for waves 0,1; C for waves 2,3 (32 VGPRs)
    const float* __restrict__ M = (wave >= 2) ? diffusion : drift;
    float Mrow[32];
#pragma unroll
    for (int k4 = 0; k4 < 8; ++k4) {
        const float4 m = *(const float4*)(M + lane * DIM + half * 32 + k4 * 4);
        Mrow[4 * k4 + 0] = m.x; Mrow[4 * k4 + 1] = m.y;
        Mrow[4 * k4 + 2] = m.z; Mrow[4 * k4 + 3] = m.w;
    }
#pragma unroll
    for (int k = 0; k < 32; ++k) asm("" : "+v"(Mrow[k]));

    const float* dWp  = dW  + (size_t)path * NSTEPS * DIM + lane;
    float*       outp = out + (size_t)path * (NSTEPS + 1) * DIM + lane;

    float bj = 0.f, dj = 0.f, x = 0.f;
    float dw0 = 0.f, dw1 = 0.f, dw2 = 0.f, dw3 = 0.f;  // wave-0 prefetch ring
    if (wave == 0) {
        bj = drift_bias[lane];
        dj = diffusion_bias[lane];
        x  = x0[path * DIM + lane];
        outp[0]  = x;                            // saved initial state
        xs[lane] = x;                            // broadcast row for step 0
        dw0 = dWp[0];
        dw1 = dWp[DIM];
        dw2 = dWp[2 * DIM];
        dw3 = dWp[3 * DIM];
    }

    __syncthreads();                             // dtp + xs ready

    float2 dts = dtp[0];                         // {dt, sdt} current step

    // consume DWCUR into dwc BEFORE the prefetch overwrites the slot
#define STEP(S, DWCUR, PF)                                                \
    {                                                                     \
        const float2 dtn = dtp[(S) + 1];                                  \
        float m0 = 0.f, m1 = 0.f, m2 = 0.f, m3 = 0.f;                     \
        _Pragma("unroll")                                                 \
        for (int k4 = 0; k4 < 8; ++k4) {                                  \
            const float4 xv = *(const float4*)(&xs[half * 32 + k4 * 4]);  \
            m0 = fmaf(Mrow[4 * k4 + 0], xv.x, m0);                        \
            m1 = fmaf(Mrow[4 * k4 + 1], xv.y, m1);                        \
            m2 = fmaf(Mrow[4 * k4 + 2], xv.z, m2);                        \
            m3 = fmaf(Mrow[4 * k4 + 3], xv.w, m3);                        \
        }                                                                 \
        const float pv = (m0 + m1) + (m2 + m3);                           \
        if (wave != 0) ps[wave - 1][lane] = pv;                           \
        __syncthreads();   /* partials ready; xs reads done */            \
        if (wave == 0) {                                                  \
            const float dwc = (DWCUR);                                    \
            if (PF) DWCUR##_pf;                                           \
            const float drift_v = (pv + ps[0][lane]) + bj;                \
            const float diff_v  = (ps[1][lane] + ps[2][lane]) + dj;       \
            x = fmaf(dts.x, drift_v, x) + diff_v * (dts.y * dwc);         \
            __builtin_nontemporal_store(x, &outp[(size_t)((S) + 1) * DIM]); \
            xs[lane] = x;                                                 \
        }                                                                 \
        dts = dtn;                                                        \
        __syncthreads();   /* xs for step S+1 published */                \
    }

#define dw0_pf dw0 = dWp[(size_t)(s + 4) * DIM]
#define dw1_pf dw1 = dWp[(size_t)(s + 5) * DIM]
#define dw2_pf dw2 = dWp[(size_t)(s + 6) * DIM]
#define dw3_pf dw3 = dWp[(size_t)(s + 7) * DIM]

    // main loop: steps 0..495, prefetching s+4..s+7 (<= 499, in range)
    for (int it = 0; it < (NSTEPS / 4) - 1; ++it) {
        const int s = it * 4;
        STEP(s + 0, dw0, 1)
        STEP(s + 1, dw1, 1)
        STEP(s + 2, dw2, 1)
        STEP(s + 3, dw3, 1)
    }
    // epilogue: steps 496..499, no prefetch
    {
        const int s = NSTEPS - 4;
        STEP(s + 0, dw0, 0)
        STEP(s + 1, dw1, 0)
        STEP(s + 2, dw2, 0)
        STEP(s + 3, dw3, 0)
    }
#undef STEP
#undef dw0_pf
#undef dw1_pf
#undef dw2_pf
#undef dw3_pf
}

extern "C" void kernel_launch(void* const* d_in, const int* in_sizes, int n_in,
                              void* d_out, int out_size, void* d_ws, size_t ws_size,
                              hipStream_t stream) {
    const float* x0             = (const float*)d_in[0];
    const float* dW             = (const float*)d_in[1];
    const float* drift          = (const float*)d_in[2];
    const float* drift_bias     = (const float*)d_in[3];
    const float* diffusion      = (const float*)d_in[4];
    const float* diffusion_bias = (const float*)d_in[5];
    const float* ts             = (const float*)d_in[6];
    float* out = (float*)d_out;

    dim3 grid(NPATH);
    dim3 block(256);
    hipLaunchKernelGGL(sde_euler_kernel, grid, block, 0, stream,
                       x0, dW, drift, drift_bias, diffusion, diffusion_bias,
                       ts, out);
}

// Round 6
// 232.513 us; speedup vs baseline: 2.3488x; 2.3488x over previous
//
#include <hip/hip_runtime.h>

#define NPATH  2048
#define DIM    64
#define NSTEPS 500

// One 64-thread block (= one wave) per path. Lane j owns x[j] and holds rows
// j of A and C in registers (128 floats). Small flat-work-group-size (64) +
// amdgpu_waves_per_eu(1,2) give the register allocator a full-file budget so
// the rows are genuinely VGPR-resident (r3/r4/r5 spilled them to scratch and
// the per-step reloads were the stall). No block barriers: single-wave
// workgroup, LDS ordering via wave_barrier + lgkmcnt only.
__attribute__((amdgpu_waves_per_eu(1, 2)))
__global__ __launch_bounds__(64) void sde_euler_kernel(
    const float* __restrict__ x0,
    const float* __restrict__ dW,
    const float* __restrict__ drift,
    const float* __restrict__ drift_bias,
    const float* __restrict__ diffusion,
    const float* __restrict__ diffusion_bias,
    const float* __restrict__ ts,
    float* __restrict__ out)
{
    __shared__ __align__(16) float xs[DIM];      // broadcast state row
    __shared__ float2 dtp[NSTEPS + 1];           // {dt, sqrt(dt)} per step

    const int lane = threadIdx.x;                // 0..63
    const int path = blockIdx.x;

    // (dt, sqrt(dt)) table — dt = ts[i+1]-ts[i] in f32, matching reference
    for (int i = lane; i < NSTEPS; i += 64) {
        const float d = ts[i + 1] - ts[i];
        dtp[i] = make_float2(d, sqrtf(d));
    }
    if (lane == 0) dtp[NSTEPS] = make_float2(0.f, 0.f);

    // Rows A[lane], C[lane] -> registers (one-time; L2-broadcast across blocks)
    float Arow[DIM], Crow[DIM];
#pragma unroll
    for (int k4 = 0; k4 < DIM / 4; ++k4) {
        const float4 a = *(const float4*)(drift + lane * DIM + k4 * 4);
        const float4 c = *(const float4*)(diffusion + lane * DIM + k4 * 4);
        Arow[4 * k4 + 0] = a.x; Arow[4 * k4 + 1] = a.y;
        Arow[4 * k4 + 2] = a.z; Arow[4 * k4 + 3] = a.w;
        Crow[4 * k4 + 0] = c.x; Crow[4 * k4 + 1] = c.y;
        Crow[4 * k4 + 2] = c.z; Crow[4 * k4 + 3] = c.w;
    }
#pragma unroll
    for (int k = 0; k < DIM; ++k) asm("" : "+v"(Arow[k]), "+v"(Crow[k]));

    const float bj = drift_bias[lane];
    const float dj = diffusion_bias[lane];

    float x = x0[path * DIM + lane];

    const float* dWp  = dW  + (size_t)path * NSTEPS * DIM + lane;
    float*       outp = out + (size_t)path * (NSTEPS + 1) * DIM + lane;
    outp[0]  = x;                                // saved initial state
    xs[lane] = x;                                // broadcast row for step 0

    // 4-deep dW prefetch ring (named regs -> static indexing, no scratch)
    float dw0 = dWp[0];
    float dw1 = dWp[DIM];
    float dw2 = dWp[2 * DIM];
    float dw3 = dWp[3 * DIM];

    __syncthreads();                             // once; single-wave, cheap

    float dt  = dtp[0].x;
    float sdt = dtp[0].y;

    // consume DWCUR into dwc BEFORE the prefetch overwrites the slot
#define STEP(S, DWCUR, PF)                                              \
    {                                                                   \
        const float dwc = (DWCUR);                                      \
        if (PF) DWCUR##_pf;                                             \
        const float2 dtn = dtp[(S) + 1];                                \
        __builtin_amdgcn_wave_barrier();                                \
        float ad0 = 0.f, ad1 = 0.f, ac0 = 0.f, ac1 = 0.f;               \
        _Pragma("unroll")                                               \
        for (int k4 = 0; k4 < DIM / 4; ++k4) {                          \
            const float4 xv = *(const float4*)(&xs[k4 * 4]);            \
            ad0 = fmaf(Arow[4 * k4 + 0], xv.x, ad0);                    \
            ac0 = fmaf(Crow[4 * k4 + 0], xv.x, ac0);                    \
            ad1 = fmaf(Arow[4 * k4 + 1], xv.y, ad1);                    \
            ac1 = fmaf(Crow[4 * k4 + 1], xv.y, ac1);                    \
            ad0 = fmaf(Arow[4 * k4 + 2], xv.z, ad0);                    \
            ac0 = fmaf(Crow[4 * k4 + 2], xv.z, ac0);                    \
            ad1 = fmaf(Arow[4 * k4 + 3], xv.w, ad1);                    \
            ac1 = fmaf(Crow[4 * k4 + 3], xv.w, ac1);                    \
        }                                                               \
        __builtin_amdgcn_wave_barrier();                                \
        const float drift_v = (ad0 + ad1) + bj;                         \
        const float diff_v  = (ac0 + ac1) + dj;                         \
        x = fmaf(dt, drift_v, x) + diff_v * (sdt * dwc);                \
        xs[lane] = x;                                                   \
        __builtin_nontemporal_store(x, &outp[(size_t)((S) + 1) * DIM]); \
        dt = dtn.x; sdt = dtn.y;                                        \
    }

#define dw0_pf dw0 = dWp[(size_t)(s + 4) * DIM]
#define dw1_pf dw1 = dWp[(size_t)(s + 5) * DIM]
#define dw2_pf dw2 = dWp[(size_t)(s + 6) * DIM]
#define dw3_pf dw3 = dWp[(size_t)(s + 7) * DIM]

    // main loop: steps 0..495, prefetching s+4..s+7 (<= 499, in range)
    for (int it = 0; it < (NSTEPS / 4) - 1; ++it) {
        const int s = it * 4;
        STEP(s + 0, dw0, 1)
        STEP(s + 1, dw1, 1)
        STEP(s + 2, dw2, 1)
        STEP(s + 3, dw3, 1)
    }
    // epilogue: steps 496..499, no prefetch
    {
        const int s = NSTEPS - 4;
        STEP(s + 0, dw0, 0)
        STEP(s + 1, dw1, 0)
        STEP(s + 2, dw2, 0)
        STEP(s + 3, dw3, 0)
    }
#undef STEP
#undef dw0_pf
#undef dw1_pf
#undef dw2_pf
#undef dw3_pf
}

extern "C" void kernel_launch(void* const* d_in, const int* in_sizes, int n_in,
                              void* d_out, int out_size, void* d_ws, size_t ws_size,
                              hipStream_t stream) {
    const float* x0             = (const float*)d_in[0];
    const float* dW             = (const float*)d_in[1];
    const float* drift          = (const float*)d_in[2];
    const float* drift_bias     = (const float*)d_in[3];
    const float* diffusion      = (const float*)d_in[4];
    const float* diffusion_bias = (const float*)d_in[5];
    const float* ts             = (const float*)d_in[6];
    float* out = (float*)d_out;

    dim3 grid(NPATH);
    dim3 block(64);
    hipLaunchKernelGGL(sde_euler_kernel, grid, block, 0, stream,
                       x0, dW, drift, drift_bias, diffusion, diffusion_bias,
                       ts, out);
}